// Round 2
// baseline (1473.102 us; speedup 1.0000x reference)
//
#include <hip/hip_runtime.h>

#define BN_EPS 1e-5f

// ---------------- CSR build ----------------

__global__ __launch_bounds__(256) void count_k(const int* __restrict__ dst, int E, int* __restrict__ cnt) {
    int i = blockIdx.x * 256 + threadIdx.x;
    if (i < E) atomicAdd(&cnt[dst[i]], 1);
}

__global__ __launch_bounds__(1024) void scan1_k(const int* __restrict__ cnt, int n, int* __restrict__ bsum) {
    __shared__ int sh[1024];
    int i = blockIdx.x * 1024 + threadIdx.x;
    sh[threadIdx.x] = (i < n) ? cnt[i] : 0;
    __syncthreads();
    for (int s = 512; s > 0; s >>= 1) {
        if (threadIdx.x < (unsigned)s) sh[threadIdx.x] += sh[threadIdx.x + s];
        __syncthreads();
    }
    if (threadIdx.x == 0) bsum[blockIdx.x] = sh[0];
}

__global__ void scan2_k(int* bsum, int nb, int* rowptr, int n, int E) {
    if (threadIdx.x == 0 && blockIdx.x == 0) {
        int run = 0;
        for (int i = 0; i < nb; ++i) { int v = bsum[i]; bsum[i] = run; run += v; }
        rowptr[n] = E;
    }
}

__global__ __launch_bounds__(1024) void scan3_k(const int* __restrict__ cnt, int n, const int* __restrict__ boff,
                                                int* __restrict__ rowptr, int* __restrict__ nxt) {
    __shared__ int sh[1024];
    int i = blockIdx.x * 1024 + threadIdx.x;
    int v = (i < n) ? cnt[i] : 0;
    sh[threadIdx.x] = v;
    __syncthreads();
    for (int s = 1; s < 1024; s <<= 1) {
        int t = (threadIdx.x >= (unsigned)s) ? sh[threadIdx.x - s] : 0;
        __syncthreads();
        sh[threadIdx.x] += t;
        __syncthreads();
    }
    if (i < n) {
        int ex = boff[blockIdx.x] + sh[threadIdx.x] - v;
        rowptr[i] = ex;
        nxt[i] = ex;
    }
}

__global__ __launch_bounds__(256) void scatter_k(const int* __restrict__ src, const int* __restrict__ dst, int E,
                                                 int* __restrict__ nxt, int* __restrict__ ssrc) {
    int i = blockIdx.x * 256 + threadIdx.x;
    if (i < E) {
        int d = dst[i];
        int p = atomicAdd(&nxt[d], 1);
        ssrc[p] = src[i];
    }
}

// ---------------- GEMM: H = f(X) @ W, f = identity (MODE 0) or BN+ReLU (MODE 1) ----------------
// Block: 256 threads, tile 128 rows x 128 cols, K chunked by 32.
// Thread tile: 8 rows (strided 16) x 8 cols. A LDS stride 36 -> 2-way (free) bank pattern on reads.

template <int MODE>
__global__ __launch_bounds__(256) void gemm_k(const float* __restrict__ X, const float* __restrict__ W,
                                              float* __restrict__ H, const float* __restrict__ ss, int n) {
    __shared__ float As[128][36];
    __shared__ float Bs[32][128];
    int tid = threadIdx.x;
    int rg = tid & 15;       // rows rg + 16*i
    int cg = tid >> 4;       // cols cg*8 .. cg*8+7
    int rowBase = blockIdx.x * 128;

    float acc[8][8];
#pragma unroll
    for (int i = 0; i < 8; ++i)
#pragma unroll
        for (int j = 0; j < 8; ++j) acc[i][j] = 0.f;

    for (int k0 = 0; k0 < 128; k0 += 32) {
        // stage A chunk: 128 rows x 32 cols
#pragma unroll
        for (int t = 0; t < 4; ++t) {
            int idx = tid + t * 256;
            int r = idx >> 3;
            int c4 = (idx & 7) * 4;
            int gr = rowBase + r;
            float4 v = make_float4(0.f, 0.f, 0.f, 0.f);
            if (gr < n) v = *(const float4*)(X + (size_t)gr * 128 + k0 + c4);
            if (MODE) {
                int c = k0 + c4;
                v.x = fmaxf(fmaf(v.x, ss[c + 0], ss[128 + c + 0]), 0.f);
                v.y = fmaxf(fmaf(v.y, ss[c + 1], ss[128 + c + 1]), 0.f);
                v.z = fmaxf(fmaf(v.z, ss[c + 2], ss[128 + c + 2]), 0.f);
                v.w = fmaxf(fmaf(v.w, ss[c + 3], ss[128 + c + 3]), 0.f);
            }
            *(float4*)&As[r][c4] = v;
        }
        // stage W chunk: rows k0..k0+31, all 128 cols
#pragma unroll
        for (int t = 0; t < 4; ++t) {
            int idx = tid + t * 256;
            int r = idx >> 5;
            int c4 = (idx & 31) * 4;
            *(float4*)&Bs[r][c4] = *(const float4*)(W + (size_t)(k0 + r) * 128 + c4);
        }
        __syncthreads();

#pragma unroll
        for (int kk = 0; kk < 32; kk += 4) {
            float4 a[8];
#pragma unroll
            for (int i = 0; i < 8; ++i) a[i] = *(const float4*)&As[rg + 16 * i][kk];
#pragma unroll
            for (int t = 0; t < 4; ++t) {
                float4 wl = *(const float4*)&Bs[kk + t][cg * 8];
                float4 wh = *(const float4*)&Bs[kk + t][cg * 8 + 4];
#pragma unroll
                for (int i = 0; i < 8; ++i) {
                    float av = (t == 0) ? a[i].x : (t == 1) ? a[i].y : (t == 2) ? a[i].z : a[i].w;
                    acc[i][0] = fmaf(av, wl.x, acc[i][0]);
                    acc[i][1] = fmaf(av, wl.y, acc[i][1]);
                    acc[i][2] = fmaf(av, wl.z, acc[i][2]);
                    acc[i][3] = fmaf(av, wl.w, acc[i][3]);
                    acc[i][4] = fmaf(av, wh.x, acc[i][4]);
                    acc[i][5] = fmaf(av, wh.y, acc[i][5]);
                    acc[i][6] = fmaf(av, wh.z, acc[i][6]);
                    acc[i][7] = fmaf(av, wh.w, acc[i][7]);
                }
            }
        }
        __syncthreads();
    }

#pragma unroll
    for (int i = 0; i < 8; ++i) {
        int gr = rowBase + rg + 16 * i;
        if (gr < n) {
            float4 v0 = make_float4(acc[i][0], acc[i][1], acc[i][2], acc[i][3]);
            float4 v1 = make_float4(acc[i][4], acc[i][5], acc[i][6], acc[i][7]);
            *(float4*)(H + (size_t)gr * 128 + cg * 8) = v0;
            *(float4*)(H + (size_t)gr * 128 + cg * 8 + 4) = v1;
        }
    }
}

// ---------------- Aggregation: out[n] = sum_{e in CSR[n]} H[src[e]] ----------------
// One wave per node (grid-strided), 2 features per lane.
// MODE 0: write + accumulate BN stats (double).  MODE 1: fused log_softmax epilogue.
// stats layout per layer: [sum 0..127 | sumsq 128..255]  (matches bnfin_k reads!)

template <int MODE>
__global__ __launch_bounds__(256) void agg_k(const float* __restrict__ H, const int* __restrict__ rowptr,
                                             const int* __restrict__ ssrc, float* __restrict__ out,
                                             double* __restrict__ stats, int n) {
    int lane = threadIdx.x & 63;
    int wid = (blockIdx.x * 256 + threadIdx.x) >> 6;
    int nw = (gridDim.x * 256) >> 6;
    const float* base = H + 2 * lane;
    double s0 = 0, s1 = 0, q0 = 0, q1 = 0;

    for (int node = wid; node < n; node += nw) {
        int beg = rowptr[node], end = rowptr[node + 1];
        float ax = 0.f, ay = 0.f;
        int e = beg;
        for (; e + 4 <= end; e += 4) {
            int sA = ssrc[e], sB = ssrc[e + 1], sC = ssrc[e + 2], sD = ssrc[e + 3];
            float2 va = *(const float2*)(base + (size_t)sA * 128);
            float2 vb = *(const float2*)(base + (size_t)sB * 128);
            float2 vc = *(const float2*)(base + (size_t)sC * 128);
            float2 vd = *(const float2*)(base + (size_t)sD * 128);
            ax += (va.x + vb.x) + (vc.x + vd.x);
            ay += (va.y + vb.y) + (vc.y + vd.y);
        }
        for (; e < end; ++e) {
            float2 v = *(const float2*)(base + (size_t)ssrc[e] * 128);
            ax += v.x;
            ay += v.y;
        }
        if (MODE == 0) {
            *(float2*)(out + (size_t)node * 128 + 2 * lane) = make_float2(ax, ay);
            s0 += ax; q0 += (double)ax * (double)ax;
            s1 += ay; q1 += (double)ay * (double)ay;
        } else {
            float m = fmaxf(ax, ay);
#pragma unroll
            for (int off = 32; off > 0; off >>= 1) m = fmaxf(m, __shfl_xor(m, off));
            float ex = expf(ax - m) + expf(ay - m);
#pragma unroll
            for (int off = 32; off > 0; off >>= 1) ex += __shfl_xor(ex, off);
            float lse = m + logf(ex);
            *(float2*)(out + (size_t)node * 128 + 2 * lane) = make_float2(ax - lse, ay - lse);
        }
    }
    if (MODE == 0) {
        atomicAdd(&stats[2 * lane], s0);
        atomicAdd(&stats[2 * lane + 1], s1);
        atomicAdd(&stats[128 + 2 * lane], q0);
        atomicAdd(&stats[128 + 2 * lane + 1], q1);
    }
}

// ---------------- BN finalize: scale/shift from stats ----------------

__global__ void bnfin_k(const double* __restrict__ stats, const float* __restrict__ gamma,
                        const float* __restrict__ beta, float* __restrict__ ss, int n) {
    int f = threadIdx.x;
    if (f < 128) {
        double mu = stats[f] / n;
        double var = stats[128 + f] / n - mu * mu;
        float rs = rsqrtf((float)var + BN_EPS);
        float sc = gamma[f] * rs;
        ss[f] = sc;
        ss[128 + f] = beta[f] - (float)mu * sc;
    }
}

// ---------------- driver ----------------

extern "C" void kernel_launch(void* const* d_in, const int* in_sizes, int n_in,
                              void* d_out, int out_size, void* d_ws, size_t ws_size,
                              hipStream_t stream) {
    const float* x = (const float*)d_in[0];
    const int* ei = (const int*)d_in[1];
    const float* Ws = (const float*)d_in[2];
    const float* gammas = (const float*)d_in[3];
    const float* betas = (const float*)d_in[4];
    int N = in_sizes[0] / 128;
    int E = in_sizes[1] / 2;
    const int* src = ei;
    const int* dst = ei + E;
    float* out = (float*)d_out;

    char* w = (char*)d_ws;
    size_t o = 0;
    auto alloc = [&](size_t bytes) { char* p = w + o; o += (bytes + 511) & ~511ull; return p; };
    float* h = (float*)alloc((size_t)N * 128 * 4);
    int* cnt = (int*)alloc((size_t)N * 4);
    int* rowptr = (int*)alloc(((size_t)N + 1) * 4);
    int* nxt = (int*)alloc((size_t)N * 4);
    int* bsum = (int*)alloc(4096);
    int* ssrc = (int*)alloc((size_t)E * 4);
    double* stats = (double*)alloc(512 * 8);  // [sum128|sq128] x 2 layers
    float* ss = (float*)alloc(512 * 4);       // [scale128|shift128] x 2 layers

    hipMemsetAsync(cnt, 0, (size_t)N * 4, stream);
    hipMemsetAsync(stats, 0, 512 * 8, stream);

    int ebl = (E + 255) / 256;
    int nb = (N + 1023) / 1024;
    count_k<<<ebl, 256, 0, stream>>>(dst, E, cnt);
    scan1_k<<<nb, 1024, 0, stream>>>(cnt, N, bsum);
    scan2_k<<<1, 64, 0, stream>>>(bsum, nb, rowptr, N, E);
    scan3_k<<<nb, 1024, 0, stream>>>(cnt, N, bsum, rowptr, nxt);
    scatter_k<<<ebl, 256, 0, stream>>>(src, dst, E, nxt, ssrc);

    int gblk = (N + 127) / 128;
    const int AGG_BLOCKS = 2048;

    // layer 0
    gemm_k<0><<<gblk, 256, 0, stream>>>(x, Ws, h, nullptr, N);
    agg_k<0><<<AGG_BLOCKS, 256, 0, stream>>>(h, rowptr, ssrc, out, stats, N);
    bnfin_k<<<1, 128, 0, stream>>>(stats, gammas, betas, ss, N);
    // layer 1 (BN0+ReLU fused into A staging)
    gemm_k<1><<<gblk, 256, 0, stream>>>(out, Ws + 16384, h, ss, N);
    agg_k<0><<<AGG_BLOCKS, 256, 0, stream>>>(h, rowptr, ssrc, out, stats + 256, N);
    bnfin_k<<<1, 128, 0, stream>>>(stats + 256, gammas + 128, betas + 128, ss + 256, N);
    // layer 2 (BN1+ReLU fused, log_softmax fused into aggregation)
    gemm_k<1><<<gblk, 256, 0, stream>>>(out, Ws + 32768, h, ss + 256, N);
    agg_k<1><<<AGG_BLOCKS, 256, 0, stream>>>(h, rowptr, ssrc, out, nullptr, N);
}